// Round 10
// baseline (338.892 us; speedup 1.0000x reference)
//
#include <hip/hip_runtime.h>
#include <hip/hip_bf16.h>
#include <stdint.h>

typedef __attribute__((ext_vector_type(8))) short bf16x8;
typedef __attribute__((ext_vector_type(4))) float f32x4;

#define GLOAD16(gptr, lptr)                                              \
  __builtin_amdgcn_global_load_lds(                                      \
      (const __attribute__((address_space(1))) void*)(gptr),             \
      (__attribute__((address_space(3))) void*)(lptr), 16, 0, 0)

__device__ __forceinline__ uint32_t pack_bf16_2(float a, float b) {
  union { __hip_bfloat16 h; unsigned short u; } ca, cb;
  ca.h = __float2bfloat16(a); cb.h = __float2bfloat16(b);
  return (uint32_t)ca.u | ((uint32_t)cb.u << 16);
}

// ------------------------------------------- prep: fused cvt(q,k,v) + wtrans(4 weights)
__global__ __launch_bounds__(256)
void prep_kernel(const float* __restrict__ q, const float* __restrict__ k,
                 const float* __restrict__ v,
                 __hip_bfloat16* __restrict__ q_bf, __hip_bfloat16* __restrict__ k_bf,
                 __hip_bfloat16* __restrict__ v_bf,
                 const float* __restrict__ w0, const float* __restrict__ w1,
                 const float* __restrict__ w2, const float* __restrict__ w3,
                 __hip_bfloat16* __restrict__ o0, __hip_bfloat16* __restrict__ o1,
                 __hip_bfloat16* __restrict__ o2, __hip_bfloat16* __restrict__ o3)
{
  const int blk = blockIdx.x;
  if (blk < 6144) {
    const int z = blk >> 11;
    const int bx = blk & 2047;
    const float* in = z == 0 ? q : z == 1 ? k : v;
    __hip_bfloat16* out = z == 0 ? q_bf : z == 1 ? k_bf : v_bf;
    long i = ((long)bx * 256 + threadIdx.x) * 8;
    float4 a = *(const float4*)(in + i);
    float4 b = *(const float4*)(in + i + 4);
    uint4 r;
    r.x = pack_bf16_2(a.x, a.y); r.y = pack_bf16_2(a.z, a.w);
    r.z = pack_bf16_2(b.x, b.y); r.w = pack_bf16_2(b.z, b.w);
    *(uint4*)(out + i) = r;
  } else {
    __shared__ float t[64][65];
    const int w = blk - 6144;
    const int z = w >> 8;
    const int by = (w >> 4) & 15, bx = w & 15;
    const float* in = z == 0 ? w0 : z == 1 ? w1 : z == 2 ? w2 : w3;
    __hip_bfloat16* out = z == 0 ? o0 : z == 1 ? o1 : z == 2 ? o2 : o3;
    const int tx = threadIdx.x & 15, ty = threadIdx.x >> 4;
    for (int i = 0; i < 4; ++i)
      for (int j = 0; j < 4; ++j)
        t[ty*4+i][tx*4+j] = in[(long)(by*64 + ty*4+i)*1024 + bx*64 + tx*4 + j];
    __syncthreads();
    for (int i = 0; i < 4; ++i)
      for (int j = 0; j < 4; ++j)
        out[(long)(bx*64 + ty*4+i)*1024 + by*64 + tx*4 + j] =
            __float2bfloat16(t[tx*4+j][ty*4+i]);
  }
}

// ------------------------------------------- V transpose: [bh][s][d] -> [bh][d][s] (bf16)
__global__ __launch_bounds__(256)
void vtrans_kernel(const __hip_bfloat16* __restrict__ in, __hip_bfloat16* __restrict__ out)
{
  __shared__ __hip_bfloat16 t[64][72];
  const int tx = threadIdx.x & 15, ty = threadIdx.x >> 4;
  const int sb = blockIdx.x, bh = blockIdx.y;
  const __hip_bfloat16* inp = in + (long)bh * 2048 * 64;
  __hip_bfloat16* outp = out + (long)bh * 64 * 2048;
  for (int i = 0; i < 4; ++i)
    for (int j = 0; j < 4; ++j)
      t[ty*4+i][tx*4+j] = inp[(long)(sb*64 + ty*4+i)*64 + tx*4 + j];
  __syncthreads();
  for (int i = 0; i < 4; ++i)
    for (int j = 0; j < 4; ++j)
      outp[(long)(ty*4+i)*2048 + sb*64 + tx*4 + j] = t[tx*4+j][ty*4+i];
}

// ---------------------------------------------------------------- 128x128 bf16 GEMM, B^T input
template<int EPI>
__global__ __launch_bounds__(256)
void gemm_bt(const __hip_bfloat16* __restrict__ A0,
             const __hip_bfloat16* __restrict__ A1,
             const __hip_bfloat16* __restrict__ A2,
             const __hip_bfloat16* __restrict__ B0,
             const __hip_bfloat16* __restrict__ B1,
             const __hip_bfloat16* __restrict__ B2,
             void* __restrict__ out,
             const float* __restrict__ bias,
             const float* __restrict__ resid,
             int M, int N, int K)
{
  const int z = (EPI == 0) ? blockIdx.z : 0;
  const __hip_bfloat16* A  = z == 0 ? A0 : z == 1 ? A1 : A2;
  const __hip_bfloat16* Bt = z == 0 ? B0 : z == 1 ? B1 : B2;
  const float scale = (EPI == 0 && z == 0) ? 0.045084219f : 1.0f;  // log2e/32

  __shared__ __hip_bfloat16 As[128*32];
  __shared__ __hip_bfloat16 Bs[128*32];
  const int tid = threadIdx.x;
  const int wid = tid >> 6;
  const int lane = tid & 63;
  const int lr = lane & 15, lg = lane >> 4;
  const int bm = blockIdx.y, bn = blockIdx.x;
  const int wm = wid >> 1, wn = wid & 1;

  f32x4 acc[4][4] = {};

  const int srow = tid >> 2;
  const int scol = (tid & 3) * 8;
  const __hip_bfloat16* Ag = A  + (long)(bm*128 + srow)*K + scol;
  const __hip_bfloat16* Bg = Bt + (long)(bn*128 + srow)*K + scol;
  __hip_bfloat16* AsW = &As[wid*512];
  __hip_bfloat16* BsW = &Bs[wid*512];

  for (int k0 = 0; k0 < K; k0 += 32) {
    GLOAD16(Ag + k0,          AsW);
    GLOAD16(Ag + 64*K + k0,   AsW + 2048);
    GLOAD16(Bg + k0,          BsW);
    GLOAD16(Bg + 64*K + k0,   BsW + 2048);
    __syncthreads();
    bf16x8 a[4], b[4];
    for (int m = 0; m < 4; ++m)
      a[m] = *(const bf16x8*)&As[(wm*64 + m*16 + lr)*32 + lg*8];
    for (int n = 0; n < 4; ++n)
      b[n] = *(const bf16x8*)&Bs[(wn*64 + n*16 + lr)*32 + lg*8];
    for (int m = 0; m < 4; ++m)
      for (int n = 0; n < 4; ++n)
        acc[m][n] = __builtin_amdgcn_mfma_f32_16x16x32_bf16(b[n], a[m], acc[m][n], 0, 0, 0);
    __syncthreads();
  }

  for (int m = 0; m < 4; ++m) {
    const int grow = bm*128 + wm*64 + m*16 + lr;
    for (int n = 0; n < 4; ++n) {
      const int c0 = bn*128 + wn*64 + n*16 + lg*4;
      if (EPI == 0) {
        const int b_ = grow >> 11, s = grow & 2047;
        const int h = c0 >> 6, d = c0 & 63;
        uint2 pk;
        pk.x = pack_bf16_2(acc[m][n][0]*scale, acc[m][n][1]*scale);
        pk.y = pack_bf16_2(acc[m][n][2]*scale, acc[m][n][3]*scale);
        *(uint2*)((__hip_bfloat16*)out + (long)z*4194304 +
                  ((long)(b_*16 + h)*2048 + s)*64 + d) = pk;
      } else {
        float4 b4 = *(const float4*)(bias + c0);
        float4 r4 = *(const float4*)(resid + (long)grow*N + c0);
        float4 o4;
        o4.x = acc[m][n][0] + b4.x + r4.x;
        o4.y = acc[m][n][1] + b4.y + r4.y;
        o4.z = acc[m][n][2] + b4.z + r4.z;
        o4.w = acc[m][n][3] + b4.w + r4.w;
        *(float4*)((float*)out + (long)grow*N + c0) = o4;
      }
    }
  }
}

// ---------------------------------------------------------------- attention
// Qh,Kh: [bh][2048][64] bf16 (Qh pre-scaled log2e/32 -> exp2); Vt: [bh][64][2048]
// KEY CHANGE vs R5: K-fragment rows loaded PERMUTED (krow = (lr>>2)*8 + nk*4 +
// (lr&3)) so the QK output lands with each lane holding P[q=lr][k = wid*32 +
// lg*8 + 0..7] — exactly PV's B-operand fragment, LANE-LOCAL. PV sums each
// wave's own k=32 window over all d (4 dt tiles, same MFMA count). Pass 2 has
// ZERO barriers / ZERO LDS / ZERO shuffles; cross-wave combine is a one-time
// 16KB acc reduction at the end. attn_out stores are 8 consecutive floats/lane
// (128B contiguous per q-row per wave). NT stores + XCD swizzle kept.
__global__ __launch_bounds__(256)
void attn_kernel(const __hip_bfloat16* __restrict__ Qh,
                 const __hip_bfloat16* __restrict__ Kh,
                 const __hip_bfloat16* __restrict__ Vt,
                 float* __restrict__ attn_out,
                 __hip_bfloat16* __restrict__ O)
{
  __shared__ float rbuf[4][16][68];
  __shared__ float red[4][64];
  __shared__ float invl[64];

  const int tid = threadIdx.x, wid = tid >> 6, lane = tid & 63;
  const int lr = lane & 15, lg = lane >> 4;
  const int orig = (blockIdx.x & 7) * 128 + (blockIdx.x >> 3);
  const int bh = orig >> 5, qb = orig & 31;

  const int krow = ((lr >> 2) << 3) + (lr & 3);   // permuted k-row within 32
  const __hip_bfloat16* Qlane = Qh + ((long)bh*2048 + qb*64 + lr)*64 + lg*8;
  const __hip_bfloat16* Klane = Kh + (long)bh*131072 + (long)(wid*32 + krow)*64 + lg*8;
  const __hip_bfloat16* Vlane = Vt + (long)bh*131072 + (long)lr*2048 + wid*32 + lg*8;
  float* attn_lane = attn_out + ((long)bh*2048 + qb*64 + lr)*2048 + wid*32 + lg*8;

  bf16x8 aq[4][2];
#pragma unroll
  for (int mq = 0; mq < 4; ++mq)
    for (int kk = 0; kk < 2; ++kk)
      aq[mq][kk] = *(const bf16x8*)(Qlane + mq*1024 + kk*32);

  // ---- pass 1: row sums of exp2(S') — barrier-free (k-permutation is sum-invariant)
  float rs[4] = {0.f, 0.f, 0.f, 0.f};
  for (int kt = 0; kt < 16; ++kt) {
    bf16x8 bk[2][2];
#pragma unroll
    for (int nk = 0; nk < 2; ++nk)
      for (int kk = 0; kk < 2; ++kk)
        bk[nk][kk] = *(const bf16x8*)(Klane + kt*8192 + nk*256 + kk*32);
#pragma unroll
    for (int mq = 0; mq < 4; ++mq) {
      f32x4 s0 = {}, s1 = {};
      for (int kk = 0; kk < 2; ++kk) {
        s0 = __builtin_amdgcn_mfma_f32_16x16x32_bf16(bk[0][kk], aq[mq][kk], s0, 0, 0, 0);
        s1 = __builtin_amdgcn_mfma_f32_16x16x32_bf16(bk[1][kk], aq[mq][kk], s1, 0, 0, 0);
      }
      for (int j = 0; j < 4; ++j)
        rs[mq] += exp2f(s0[j]) + exp2f(s1[j]);
    }
  }

#pragma unroll
  for (int mq = 0; mq < 4; ++mq) {
    float e = rs[mq];
    e += __shfl_xor(e, 16);
    e += __shfl_xor(e, 32);
    rs[mq] = e;
  }
  if (lg == 0)
    for (int mq = 0; mq < 4; ++mq)
      red[wid][mq*16 + lr] = rs[mq];
  __syncthreads();
  if (tid < 64)
    invl[tid] = 1.0f / (red[0][tid] + red[1][tid] + red[2][tid] + red[3][tid]);
  __syncthreads();

  float iv[4];
#pragma unroll
  for (int mq = 0; mq < 4; ++mq) iv[mq] = invl[mq*16 + lr];

  // ---- pass 2: barrier-free, LDS-free
  f32x4 acc[4][4] = {};

#pragma unroll 1
  for (int kt = 0; kt < 16; ++kt) {
    bf16x8 bk[2][2], vb[4];
#pragma unroll
    for (int nk = 0; nk < 2; ++nk)
      for (int kk = 0; kk < 2; ++kk)
        bk[nk][kk] = *(const bf16x8*)(Klane + kt*8192 + nk*256 + kk*32);
#pragma unroll
    for (int dt = 0; dt < 4; ++dt)
      vb[dt] = *(const bf16x8*)(Vlane + dt*32768 + kt*128);

#pragma unroll
    for (int mq = 0; mq < 4; ++mq) {
      f32x4 s0 = {}, s1 = {};
      __builtin_amdgcn_s_setprio(1);
      for (int kk = 0; kk < 2; ++kk) {
        s0 = __builtin_amdgcn_mfma_f32_16x16x32_bf16(bk[0][kk], aq[mq][kk], s0, 0, 0, 0);
        s1 = __builtin_amdgcn_mfma_f32_16x16x32_bf16(bk[1][kk], aq[mq][kk], s1, 0, 0, 0);
      }
      __builtin_amdgcn_s_setprio(0);

      const float ivm = iv[mq];
      f32x4 plo, phi;
      plo[0] = exp2f(s0[0]) * ivm; plo[1] = exp2f(s0[1]) * ivm;
      plo[2] = exp2f(s0[2]) * ivm; plo[3] = exp2f(s0[3]) * ivm;
      phi[0] = exp2f(s1[0]) * ivm; phi[1] = exp2f(s1[1]) * ivm;
      phi[2] = exp2f(s1[2]) * ivm; phi[3] = exp2f(s1[3]) * ivm;

      float* dst = attn_lane + (long)(mq*16)*2048 + kt*128;
      __builtin_nontemporal_store(plo, (f32x4*)dst);
      __builtin_nontemporal_store(phi, (f32x4*)(dst + 4));

      union { bf16x8 v; uint32_t w[4]; } pa;
      pa.w[0] = pack_bf16_2(plo[0], plo[1]);
      pa.w[1] = pack_bf16_2(plo[2], plo[3]);
      pa.w[2] = pack_bf16_2(phi[0], phi[1]);
      pa.w[3] = pack_bf16_2(phi[2], phi[3]);

      __builtin_amdgcn_s_setprio(1);
      for (int dt = 0; dt < 4; ++dt)
        acc[mq][dt] = __builtin_amdgcn_mfma_f32_16x16x32_bf16(vb[dt], pa.v, acc[mq][dt], 0, 0, 0);
      __builtin_amdgcn_s_setprio(0);
    }
  }

  // ---- cross-wave acc reduction (each wave holds a partial over its k-window)
  const int b_ = bh >> 4, h = bh & 15;
  const int qq = tid >> 4, d0 = (tid & 15) * 4;
#pragma unroll 1
  for (int mq = 0; mq < 4; ++mq) {
    __syncthreads();
#pragma unroll
    for (int dt = 0; dt < 4; ++dt)
      *(f32x4*)&rbuf[wid][lr][dt*16 + lg*4] = acc[mq][dt];
    __syncthreads();
    f32x4 a0 = *(const f32x4*)&rbuf[0][qq][d0];
    f32x4 a1 = *(const f32x4*)&rbuf[1][qq][d0];
    f32x4 a2 = *(const f32x4*)&rbuf[2][qq][d0];
    f32x4 a3 = *(const f32x4*)&rbuf[3][qq][d0];
    f32x4 s = (a0 + a1) + (a2 + a3);
    uint2 pk;
    pk.x = pack_bf16_2(s[0], s[1]);
    pk.y = pack_bf16_2(s[2], s[3]);
    *(uint2*)(O + (long)(b_*2048 + qb*64 + mq*16 + qq)*1024 + h*64 + d0) = pk;
  }
}

// ---------------------------------------------------------------- layernorm
__global__ __launch_bounds__(256)
void ln_kernel(const float* __restrict__ xin, const float* __restrict__ gam,
               const float* __restrict__ bet, float* __restrict__ xout)
{
  const int row = blockIdx.x;
  const int tid = threadIdx.x;
  const float* xr = xin + (long)row*1024;
  float4 v = *(const float4*)(xr + tid*4);
  float s  = v.x + v.y + v.z + v.w;
  float ss = v.x*v.x + v.y*v.y + v.z*v.z + v.w*v.w;
  for (int o = 1; o < 64; o <<= 1) {
    s  += __shfl_xor(s, o, 64);
    ss += __shfl_xor(ss, o, 64);
  }
  __shared__ float rsh[4], rssh[4];
  const int wid = tid >> 6, lane = tid & 63;
  if (lane == 0) { rsh[wid] = s; rssh[wid] = ss; }
  __syncthreads();
  s  = rsh[0] + rsh[1] + rsh[2] + rsh[3];
  ss = rssh[0] + rssh[1] + rssh[2] + rssh[3];
  const float mean = s * (1.0f/1024.0f);
  const float var  = ss * (1.0f/1024.0f) - mean*mean;
  const float rstd = rsqrtf(var + 1e-5f);
  float4 g4 = *(const float4*)(gam + tid*4);
  float4 b4 = *(const float4*)(bet + tid*4);
  float4 o4;
  o4.x = (v.x - mean)*rstd*g4.x + b4.x;
  o4.y = (v.y - mean)*rstd*g4.y + b4.y;
  o4.z = (v.z - mean)*rstd*g4.z + b4.z;
  o4.w = (v.w - mean)*rstd*g4.w + b4.w;
  *(float4*)(xout + (long)row*1024 + tid*4) = o4;
}

// ---------------------------------------------------------------- launch
extern "C" void kernel_launch(void* const* d_in, const int* in_sizes, int n_in,
                              void* d_out, int out_size, void* d_ws, size_t ws_size,
                              hipStream_t stream)
{
  (void)in_sizes; (void)n_in; (void)out_size; (void)ws_size;
  const float* q    = (const float*)d_in[0];
  const float* k    = (const float*)d_in[1];
  const float* v    = (const float*)d_in[2];
  const float* w_q  = (const float*)d_in[3];
  const float* w_k  = (const float*)d_in[4];
  const float* w_v  = (const float*)d_in[5];
  const float* w_fc = (const float*)d_in[6];
  const float* b_fc = (const float*)d_in[7];
  const float* ln_g = (const float*)d_in[8];
  const float* ln_b = (const float*)d_in[9];

  const long MB = 1024*1024;
  char* ws = (char*)d_ws;
  __hip_bfloat16* q_bf  = (__hip_bfloat16*)(ws);
  __hip_bfloat16* k_bf  = (__hip_bfloat16*)(ws +  8*MB);
  __hip_bfloat16* v_bf  = (__hip_bfloat16*)(ws + 16*MB);
  __hip_bfloat16* wq_t  = (__hip_bfloat16*)(ws + 24*MB);
  __hip_bfloat16* wk_t  = (__hip_bfloat16*)(ws + 26*MB);
  __hip_bfloat16* wv_t  = (__hip_bfloat16*)(ws + 28*MB);
  __hip_bfloat16* wfc_t = (__hip_bfloat16*)(ws + 30*MB);
  __hip_bfloat16* QKVh  = (__hip_bfloat16*)(ws + 32*MB);   // Qh|Kh|Vh, 8MB each
  __hip_bfloat16* Qh    = QKVh;
  __hip_bfloat16* Kh    = QKVh + 4194304L;
  __hip_bfloat16* Vh    = QKVh + 8388608L;
  __hip_bfloat16* Vht   = (__hip_bfloat16*)(ws + 56*MB);
  __hip_bfloat16* Obuf  = (__hip_bfloat16*)(ws + 64*MB);
  float*          xbuf  = (float*)(ws + 72*MB);

  float* x_out    = (float*)d_out;
  float* attn_out = x_out + 4194304L;

  prep_kernel<<<7168, 256, 0, stream>>>(q, k, v, q_bf, k_bf, v_bf,
                                        w_q, w_k, w_v, w_fc,
                                        wq_t, wk_t, wv_t, wfc_t);

  gemm_bt<0><<<dim3(8, 32, 3), 256, 0, stream>>>(q_bf, k_bf, v_bf,
                                                 wq_t, wk_t, wv_t,
                                                 QKVh, nullptr, nullptr, 4096, 1024, 1024);

  vtrans_kernel<<<dim3(32, 32), 256, 0, stream>>>(Vh, Vht);

  attn_kernel<<<1024, 256, 0, stream>>>(Qh, Kh, Vht, attn_out, Obuf);

  gemm_bt<2><<<dim3(8, 32), 256, 0, stream>>>(Obuf, nullptr, nullptr,
                                              wfc_t, nullptr, nullptr,
                                              xbuf, b_fc, q, 4096, 1024, 1024);

  ln_kernel<<<4096, 256, 0, stream>>>(xbuf, ln_g, ln_b, x_out);
}

// Round 11
// 277.032 us; speedup vs baseline: 1.2233x; 1.2233x over previous
//
#include <hip/hip_runtime.h>
#include <hip/hip_bf16.h>
#include <stdint.h>

typedef __attribute__((ext_vector_type(8))) short bf16x8;
typedef __attribute__((ext_vector_type(4))) float f32x4;

#define GLOAD16(gptr, lptr)                                              \
  __builtin_amdgcn_global_load_lds(                                      \
      (const __attribute__((address_space(1))) void*)(gptr),             \
      (__attribute__((address_space(3))) void*)(lptr), 16, 0, 0)

__device__ __forceinline__ uint32_t pack_bf16_2(float a, float b) {
  union { __hip_bfloat16 h; unsigned short u; } ca, cb;
  ca.h = __float2bfloat16(a); cb.h = __float2bfloat16(b);
  return (uint32_t)ca.u | ((uint32_t)cb.u << 16);
}

// ------------------------------------------- prep: fused cvt(q,k,v) + wtrans(4 weights)
__global__ __launch_bounds__(256)
void prep_kernel(const float* __restrict__ q, const float* __restrict__ k,
                 const float* __restrict__ v,
                 __hip_bfloat16* __restrict__ q_bf, __hip_bfloat16* __restrict__ k_bf,
                 __hip_bfloat16* __restrict__ v_bf,
                 const float* __restrict__ w0, const float* __restrict__ w1,
                 const float* __restrict__ w2, const float* __restrict__ w3,
                 __hip_bfloat16* __restrict__ o0, __hip_bfloat16* __restrict__ o1,
                 __hip_bfloat16* __restrict__ o2, __hip_bfloat16* __restrict__ o3)
{
  const int blk = blockIdx.x;
  if (blk < 6144) {
    const int z = blk >> 11;
    const int bx = blk & 2047;
    const float* in = z == 0 ? q : z == 1 ? k : v;
    __hip_bfloat16* out = z == 0 ? q_bf : z == 1 ? k_bf : v_bf;
    long i = ((long)bx * 256 + threadIdx.x) * 8;
    float4 a = *(const float4*)(in + i);
    float4 b = *(const float4*)(in + i + 4);
    uint4 r;
    r.x = pack_bf16_2(a.x, a.y); r.y = pack_bf16_2(a.z, a.w);
    r.z = pack_bf16_2(b.x, b.y); r.w = pack_bf16_2(b.z, b.w);
    *(uint4*)(out + i) = r;
  } else {
    __shared__ float t[64][65];
    const int w = blk - 6144;
    const int z = w >> 8;
    const int by = (w >> 4) & 15, bx = w & 15;
    const float* in = z == 0 ? w0 : z == 1 ? w1 : z == 2 ? w2 : w3;
    __hip_bfloat16* out = z == 0 ? o0 : z == 1 ? o1 : z == 2 ? o2 : o3;
    const int tx = threadIdx.x & 15, ty = threadIdx.x >> 4;
    for (int i = 0; i < 4; ++i)
      for (int j = 0; j < 4; ++j)
        t[ty*4+i][tx*4+j] = in[(long)(by*64 + ty*4+i)*1024 + bx*64 + tx*4 + j];
    __syncthreads();
    for (int i = 0; i < 4; ++i)
      for (int j = 0; j < 4; ++j)
        out[(long)(bx*64 + ty*4+i)*1024 + by*64 + tx*4 + j] =
            __float2bfloat16(t[tx*4+j][ty*4+i]);
  }
}

// ------------------------------------------- V transpose: [bh][s][d] -> [bh][d][s] (bf16)
__global__ __launch_bounds__(256)
void vtrans_kernel(const __hip_bfloat16* __restrict__ in, __hip_bfloat16* __restrict__ out)
{
  __shared__ __hip_bfloat16 t[64][72];
  const int tx = threadIdx.x & 15, ty = threadIdx.x >> 4;
  const int sb = blockIdx.x, bh = blockIdx.y;
  const __hip_bfloat16* inp = in + (long)bh * 2048 * 64;
  __hip_bfloat16* outp = out + (long)bh * 64 * 2048;
  for (int i = 0; i < 4; ++i)
    for (int j = 0; j < 4; ++j)
      t[ty*4+i][tx*4+j] = inp[(long)(sb*64 + ty*4+i)*64 + tx*4 + j];
  __syncthreads();
  for (int i = 0; i < 4; ++i)
    for (int j = 0; j < 4; ++j)
      outp[(long)(ty*4+i)*2048 + sb*64 + tx*4 + j] = t[tx*4+j][ty*4+i];
}

// ---------------------------------------------------------------- 128x128 bf16 GEMM, B^T input
// m97 structure: global_load_lds width-16 staging for BOTH A and B (bf16).
// Swapped-operand MFMA -> lane = output row, regs = 4 consecutive output cols.
// EPI 0: fused QKV projections (blockIdx.z), bf16 out [b][h][s][d]
// EPI 2: f32 out + bias[col] + resid, float4 stores
template<int EPI>
__global__ __launch_bounds__(256)
void gemm_bt(const __hip_bfloat16* __restrict__ A0,
             const __hip_bfloat16* __restrict__ A1,
             const __hip_bfloat16* __restrict__ A2,
             const __hip_bfloat16* __restrict__ B0,
             const __hip_bfloat16* __restrict__ B1,
             const __hip_bfloat16* __restrict__ B2,
             void* __restrict__ out,
             const float* __restrict__ bias,
             const float* __restrict__ resid,
             int M, int N, int K)
{
  const int z = (EPI == 0) ? blockIdx.z : 0;
  const __hip_bfloat16* A  = z == 0 ? A0 : z == 1 ? A1 : A2;
  const __hip_bfloat16* Bt = z == 0 ? B0 : z == 1 ? B1 : B2;
  // fold log2(e) into the Q scale so attn uses exp2 directly
  const float scale = (EPI == 0 && z == 0) ? 0.045084219f : 1.0f;

  __shared__ __hip_bfloat16 As[128*32];
  __shared__ __hip_bfloat16 Bs[128*32];
  const int tid = threadIdx.x;
  const int wid = tid >> 6;
  const int lane = tid & 63;
  const int lr = lane & 15, lg = lane >> 4;
  const int bm = blockIdx.y, bn = blockIdx.x;
  const int wm = wid >> 1, wn = wid & 1;

  f32x4 acc[4][4] = {};

  const int srow = tid >> 2;          // 0..63
  const int scol = (tid & 3) * 8;
  const __hip_bfloat16* Ag = A  + (long)(bm*128 + srow)*K + scol;
  const __hip_bfloat16* Bg = Bt + (long)(bn*128 + srow)*K + scol;
  __hip_bfloat16* AsW = &As[wid*512];
  __hip_bfloat16* BsW = &Bs[wid*512];

  for (int k0 = 0; k0 < K; k0 += 32) {
    GLOAD16(Ag + k0,          AsW);
    GLOAD16(Ag + 64*K + k0,   AsW + 2048);
    GLOAD16(Bg + k0,          BsW);
    GLOAD16(Bg + 64*K + k0,   BsW + 2048);
    __syncthreads();
    bf16x8 a[4], b[4];
    for (int m = 0; m < 4; ++m)
      a[m] = *(const bf16x8*)&As[(wm*64 + m*16 + lr)*32 + lg*8];
    for (int n = 0; n < 4; ++n)
      b[n] = *(const bf16x8*)&Bs[(wn*64 + n*16 + lr)*32 + lg*8];
    for (int m = 0; m < 4; ++m)
      for (int n = 0; n < 4; ++n)
        acc[m][n] = __builtin_amdgcn_mfma_f32_16x16x32_bf16(b[n], a[m], acc[m][n], 0, 0, 0);
    __syncthreads();
  }

  for (int m = 0; m < 4; ++m) {
    const int grow = bm*128 + wm*64 + m*16 + lr;
    for (int n = 0; n < 4; ++n) {
      const int c0 = bn*128 + wn*64 + n*16 + lg*4;
      if (EPI == 0) {
        const int b_ = grow >> 11, s = grow & 2047;
        const int h = c0 >> 6, d = c0 & 63;
        uint2 pk;
        pk.x = pack_bf16_2(acc[m][n][0]*scale, acc[m][n][1]*scale);
        pk.y = pack_bf16_2(acc[m][n][2]*scale, acc[m][n][3]*scale);
        *(uint2*)((__hip_bfloat16*)out + (long)z*4194304 +
                  ((long)(b_*16 + h)*2048 + s)*64 + d) = pk;
      } else {
        float4 b4 = *(const float4*)(bias + c0);
        float4 r4 = *(const float4*)(resid + (long)grow*N + c0);
        float4 o4;
        o4.x = acc[m][n][0] + b4.x + r4.x;
        o4.y = acc[m][n][1] + b4.y + r4.y;
        o4.z = acc[m][n][2] + b4.z + r4.z;
        o4.w = acc[m][n][3] + b4.w + r4.w;
        *(float4*)((float*)out + (long)grow*N + c0) = o4;
      }
    }
  }
}

// ---------------------------------------------------------------- attention (R5 verbatim — best measured 278.5us)
// Qh,Kh: [bh][2048][64] bf16 (Qh pre-scaled by log2e/32 -> exp2); Vt: [bh][64][2048]
// K/V/Q direct-from-global (L2-resident); attn_out via NT stores; XCD swizzle;
// pass-2 register K/V prefetch + setprio; Ps XOR-swizzled, 2x __syncthreads/kt.
__global__ __launch_bounds__(256)
void attn_kernel(const __hip_bfloat16* __restrict__ Qh,
                 const __hip_bfloat16* __restrict__ Kh,
                 const __hip_bfloat16* __restrict__ Vt,
                 float* __restrict__ attn_out,
                 __hip_bfloat16* __restrict__ O)
{
  __shared__ __hip_bfloat16 Ps[64*128];
  __shared__ float red[4][64];
  __shared__ float invl[64];

  const int tid = threadIdx.x, wid = tid >> 6, lane = tid & 63;
  const int lr = lane & 15, lg = lane >> 4;
  // XCD swizzle: physical block b (XCD = b%8) -> logical orig = (b%8)*128 + b/8
  const int orig = (blockIdx.x & 7) * 128 + (blockIdx.x >> 3);
  const int bh = orig >> 5, qb = orig & 31;

  const __hip_bfloat16* Qlane = Qh + ((long)bh*2048 + qb*64 + lr)*64 + lg*8;
  const __hip_bfloat16* Klane = Kh + (long)bh*2048*64 + (long)(wid*32 + lr)*64 + lg*8;
  const __hip_bfloat16* Vlane = Vt + (long)bh*64*2048 + (long)(wid*16 + lr)*2048 + lg*8;

  bf16x8 aq[4][2];
  for (int mq = 0; mq < 4; ++mq)
    for (int kk = 0; kk < 2; ++kk)
      aq[mq][kk] = *(const bf16x8*)(Qlane + mq*1024 + kk*32);

  // ---- pass 1: row sums of exp2(S') — barrier-free
  float rs[4] = {0.f, 0.f, 0.f, 0.f};
  for (int kt = 0; kt < 16; ++kt) {
    bf16x8 bk[2][2];
    for (int nk = 0; nk < 2; ++nk)
      for (int kk = 0; kk < 2; ++kk)
        bk[nk][kk] = *(const bf16x8*)(Klane + kt*8192 + nk*1024 + kk*32);
    f32x4 s2[4][2] = {};
    for (int mq = 0; mq < 4; ++mq)
      for (int nk = 0; nk < 2; ++nk)
        for (int kk = 0; kk < 2; ++kk)
          s2[mq][nk] = __builtin_amdgcn_mfma_f32_16x16x32_bf16(bk[nk][kk], aq[mq][kk], s2[mq][nk], 0, 0, 0);
    for (int mq = 0; mq < 4; ++mq)
      for (int nk = 0; nk < 2; ++nk)
        for (int jj = 0; jj < 4; ++jj)
          rs[mq] += exp2f(s2[mq][nk][jj]);
  }

  for (int mq = 0; mq < 4; ++mq) {
    float e = rs[mq];
    e += __shfl_xor(e, 16);
    e += __shfl_xor(e, 32);
    rs[mq] = e;
  }
  if (lg == 0)
    for (int mq = 0; mq < 4; ++mq)
      red[wid][mq*16 + lr] = rs[mq];
  __syncthreads();
  if (tid < 64)
    invl[tid] = 1.0f / (red[0][tid] + red[1][tid] + red[2][tid] + red[3][tid]);
  __syncthreads();

  float iv[4];
  for (int mq = 0; mq < 4; ++mq) iv[mq] = invl[mq*16 + lr];

  // ---- pass 2 (register K/V double-buffer prefetch)
  f32x4 acc_o[4] = {};
  float* attn_row = attn_out + ((long)bh*2048 + qb*64)*2048;

  bf16x8 bk[2][2], vb[4];
#pragma unroll
  for (int nk = 0; nk < 2; ++nk)
    for (int kk = 0; kk < 2; ++kk)
      bk[nk][kk] = *(const bf16x8*)(Klane + nk*1024 + kk*32);
#pragma unroll
  for (int k2 = 0; k2 < 4; ++k2)
    vb[k2] = *(const bf16x8*)(Vlane + k2*32);

#pragma unroll 1
  for (int kt = 0; kt < 16; ++kt) {
    f32x4 s2[4][2] = {};
    __builtin_amdgcn_s_setprio(1);
#pragma unroll
    for (int mq = 0; mq < 4; ++mq)
      for (int nk = 0; nk < 2; ++nk)
        for (int kk = 0; kk < 2; ++kk)
          s2[mq][nk] = __builtin_amdgcn_mfma_f32_16x16x32_bf16(bk[nk][kk], aq[mq][kk], s2[mq][nk], 0, 0, 0);
    __builtin_amdgcn_s_setprio(0);

    // prefetch next tile's K/V fragments (land during exp/store phase)
    bf16x8 nbk[2][2], nvb[4];
    if (kt < 15) {
#pragma unroll
      for (int nk = 0; nk < 2; ++nk)
        for (int kk = 0; kk < 2; ++kk)
          nbk[nk][kk] = *(const bf16x8*)(Klane + (kt+1)*8192 + nk*1024 + kk*32);
#pragma unroll
      for (int k2 = 0; k2 < 4; ++k2)
        nvb[k2] = *(const bf16x8*)(Vlane + (kt+1)*128 + k2*32);
    }

#pragma unroll
    for (int mq = 0; mq < 4; ++mq) {
      const int row = mq*16 + lr;
      for (int nk = 0; nk < 2; ++nk) {
        const int kc = wid*32 + nk*16 + lg*4;
        f32x4 p;
        p[0] = exp2f(s2[mq][nk][0]) * iv[mq];
        p[1] = exp2f(s2[mq][nk][1]) * iv[mq];
        p[2] = exp2f(s2[mq][nk][2]) * iv[mq];
        p[3] = exp2f(s2[mq][nk][3]) * iv[mq];
        __builtin_nontemporal_store(p, (f32x4*)(attn_row + (long)row*2048 + kt*128 + kc));
        uint2 pb;
        pb.x = pack_bf16_2(p[0], p[1]);
        pb.y = pack_bf16_2(p[2], p[3]);
        const int boff = (row*256 + kc*2) ^ ((row & 15) << 4);
        *(uint2*)((char*)Ps + boff) = pb;
      }
    }
    __syncthreads();

    __builtin_amdgcn_s_setprio(1);
#pragma unroll
    for (int mq = 0; mq < 4; ++mq) {
      const int row = mq*16 + lr;
      for (int k2 = 0; k2 < 4; ++k2) {
        const int boff = (row*256 + (k2*32 + lg*8)*2) ^ ((row & 15) << 4);
        bf16x8 pa = *(const bf16x8*)((char*)Ps + boff);
        acc_o[mq] = __builtin_amdgcn_mfma_f32_16x16x32_bf16(vb[k2], pa, acc_o[mq], 0, 0, 0);
      }
    }
    __builtin_amdgcn_s_setprio(0);
    __syncthreads();

#pragma unroll
    for (int nk = 0; nk < 2; ++nk)
      for (int kk = 0; kk < 2; ++kk)
        bk[nk][kk] = nbk[nk][kk];
#pragma unroll
    for (int k2 = 0; k2 < 4; ++k2)
      vb[k2] = nvb[k2];
  }

  const int b_ = bh >> 4, h = bh & 15;
  for (int mq = 0; mq < 4; ++mq) {
    const long grow = (long)b_*2048 + qb*64 + mq*16 + lr;
    const int col = h*64 + wid*16 + lg*4;
    uint2 pk;
    pk.x = pack_bf16_2(acc_o[mq][0], acc_o[mq][1]);
    pk.y = pack_bf16_2(acc_o[mq][2], acc_o[mq][3]);
    *(uint2*)(O + grow*1024 + col) = pk;
  }
}

// ---------------------------------------------------------------- layernorm
__global__ __launch_bounds__(256)
void ln_kernel(const float* __restrict__ xin, const float* __restrict__ gam,
               const float* __restrict__ bet, float* __restrict__ xout)
{
  const int row = blockIdx.x;
  const int tid = threadIdx.x;
  const float* xr = xin + (long)row*1024;
  float4 v = *(const float4*)(xr + tid*4);
  float s  = v.x + v.y + v.z + v.w;
  float ss = v.x*v.x + v.y*v.y + v.z*v.z + v.w*v.w;
  for (int o = 1; o < 64; o <<= 1) {
    s  += __shfl_xor(s, o, 64);
    ss += __shfl_xor(ss, o, 64);
  }
  __shared__ float rsh[4], rssh[4];
  const int wid = tid >> 6, lane = tid & 63;
  if (lane == 0) { rsh[wid] = s; rssh[wid] = ss; }
  __syncthreads();
  s  = rsh[0] + rsh[1] + rsh[2] + rsh[3];
  ss = rssh[0] + rssh[1] + rssh[2] + rssh[3];
  const float mean = s * (1.0f/1024.0f);
  const float var  = ss * (1.0f/1024.0f) - mean*mean;
  const float rstd = rsqrtf(var + 1e-5f);
  float4 g4 = *(const float4*)(gam + tid*4);
  float4 b4 = *(const float4*)(bet + tid*4);
  float4 o4;
  o4.x = (v.x - mean)*rstd*g4.x + b4.x;
  o4.y = (v.y - mean)*rstd*g4.y + b4.y;
  o4.z = (v.z - mean)*rstd*g4.z + b4.z;
  o4.w = (v.w - mean)*rstd*g4.w + b4.w;
  *(float4*)(xout + (long)row*1024 + tid*4) = o4;
}

// ---------------------------------------------------------------- launch
extern "C" void kernel_launch(void* const* d_in, const int* in_sizes, int n_in,
                              void* d_out, int out_size, void* d_ws, size_t ws_size,
                              hipStream_t stream)
{
  (void)in_sizes; (void)n_in; (void)out_size; (void)ws_size;
  const float* q    = (const float*)d_in[0];
  const float* k    = (const float*)d_in[1];
  const float* v    = (const float*)d_in[2];
  const float* w_q  = (const float*)d_in[3];
  const float* w_k  = (const float*)d_in[4];
  const float* w_v  = (const float*)d_in[5];
  const float* w_fc = (const float*)d_in[6];
  const float* b_fc = (const float*)d_in[7];
  const float* ln_g = (const float*)d_in[8];
  const float* ln_b = (const float*)d_in[9];

  const long MB = 1024*1024;
  char* ws = (char*)d_ws;
  __hip_bfloat16* q_bf  = (__hip_bfloat16*)(ws);
  __hip_bfloat16* k_bf  = (__hip_bfloat16*)(ws +  8*MB);
  __hip_bfloat16* v_bf  = (__hip_bfloat16*)(ws + 16*MB);
  __hip_bfloat16* wq_t  = (__hip_bfloat16*)(ws + 24*MB);
  __hip_bfloat16* wk_t  = (__hip_bfloat16*)(ws + 26*MB);
  __hip_bfloat16* wv_t  = (__hip_bfloat16*)(ws + 28*MB);
  __hip_bfloat16* wfc_t = (__hip_bfloat16*)(ws + 30*MB);
  __hip_bfloat16* QKVh  = (__hip_bfloat16*)(ws + 32*MB);   // Qh|Kh|Vh, 8MB each
  __hip_bfloat16* Qh    = QKVh;
  __hip_bfloat16* Kh    = QKVh + 4194304L;
  __hip_bfloat16* Vh    = QKVh + 8388608L;
  __hip_bfloat16* Vht   = (__hip_bfloat16*)(ws + 56*MB);
  __hip_bfloat16* Obuf  = (__hip_bfloat16*)(ws + 64*MB);
  float*          xbuf  = (float*)(ws + 72*MB);

  float* x_out    = (float*)d_out;
  float* attn_out = x_out + 4194304L;

  prep_kernel<<<7168, 256, 0, stream>>>(q, k, v, q_bf, k_bf, v_bf,
                                        w_q, w_k, w_v, w_fc,
                                        wq_t, wk_t, wv_t, wfc_t);

  gemm_bt<0><<<dim3(8, 32, 3), 256, 0, stream>>>(q_bf, k_bf, v_bf,
                                                 wq_t, wk_t, wv_t,
                                                 QKVh, nullptr, nullptr, 4096, 1024, 1024);

  vtrans_kernel<<<dim3(32, 32), 256, 0, stream>>>(Vh, Vht);

  attn_kernel<<<1024, 256, 0, stream>>>(Qh, Kh, Vht, attn_out, Obuf);

  gemm_bt<2><<<dim3(8, 32), 256, 0, stream>>>(Obuf, nullptr, nullptr,
                                              wfc_t, nullptr, nullptr,
                                              xbuf, b_fc, q, 4096, 1024, 1024);

  ln_kernel<<<4096, 256, 0, stream>>>(xbuf, ln_g, ln_b, x_out);
}

// Round 12
// 265.924 us; speedup vs baseline: 1.2744x; 1.0418x over previous
//
#include <hip/hip_runtime.h>
#include <hip/hip_bf16.h>
#include <stdint.h>

typedef __attribute__((ext_vector_type(8))) short bf16x8;
typedef __attribute__((ext_vector_type(4))) float f32x4;

#define GLOAD16(gptr, lptr)                                              \
  __builtin_amdgcn_global_load_lds(                                      \
      (const __attribute__((address_space(1))) void*)(gptr),             \
      (__attribute__((address_space(3))) void*)(lptr), 16, 0, 0)

__device__ __forceinline__ uint32_t pack_bf16_2(float a, float b) {
  union { __hip_bfloat16 h; unsigned short u; } ca, cb;
  ca.h = __float2bfloat16(a); cb.h = __float2bfloat16(b);
  return (uint32_t)ca.u | ((uint32_t)cb.u << 16);
}

// ------------------------------------------- prep: fused cvt(q,k,v) + wtrans(4 weights)
__global__ __launch_bounds__(256)
void prep_kernel(const float* __restrict__ q, const float* __restrict__ k,
                 const float* __restrict__ v,
                 __hip_bfloat16* __restrict__ q_bf, __hip_bfloat16* __restrict__ k_bf,
                 __hip_bfloat16* __restrict__ v_bf,
                 const float* __restrict__ w0, const float* __restrict__ w1,
                 const float* __restrict__ w2, const float* __restrict__ w3,
                 __hip_bfloat16* __restrict__ o0, __hip_bfloat16* __restrict__ o1,
                 __hip_bfloat16* __restrict__ o2, __hip_bfloat16* __restrict__ o3)
{
  const int blk = blockIdx.x;
  if (blk < 6144) {
    const int z = blk >> 11;
    const int bx = blk & 2047;
    const float* in = z == 0 ? q : z == 1 ? k : v;
    __hip_bfloat16* out = z == 0 ? q_bf : z == 1 ? k_bf : v_bf;
    long i = ((long)bx * 256 + threadIdx.x) * 8;
    float4 a = *(const float4*)(in + i);
    float4 b = *(const float4*)(in + i + 4);
    uint4 r;
    r.x = pack_bf16_2(a.x, a.y); r.y = pack_bf16_2(a.z, a.w);
    r.z = pack_bf16_2(b.x, b.y); r.w = pack_bf16_2(b.z, b.w);
    *(uint4*)(out + i) = r;
  } else {
    __shared__ float t[64][65];
    const int w = blk - 6144;
    const int z = w >> 8;
    const int by = (w >> 4) & 15, bx = w & 15;
    const float* in = z == 0 ? w0 : z == 1 ? w1 : z == 2 ? w2 : w3;
    __hip_bfloat16* out = z == 0 ? o0 : z == 1 ? o1 : z == 2 ? o2 : o3;
    const int tx = threadIdx.x & 15, ty = threadIdx.x >> 4;
    for (int i = 0; i < 4; ++i)
      for (int j = 0; j < 4; ++j)
        t[ty*4+i][tx*4+j] = in[(long)(by*64 + ty*4+i)*1024 + bx*64 + tx*4 + j];
    __syncthreads();
    for (int i = 0; i < 4; ++i)
      for (int j = 0; j < 4; ++j)
        out[(long)(bx*64 + ty*4+i)*1024 + by*64 + tx*4 + j] =
            __float2bfloat16(t[tx*4+j][ty*4+i]);
  }
}

// ------------------------------------------- V transpose: [bh][s][d] -> [bh][d][s] (bf16)
__global__ __launch_bounds__(256)
void vtrans_kernel(const __hip_bfloat16* __restrict__ in, __hip_bfloat16* __restrict__ out)
{
  __shared__ __hip_bfloat16 t[64][72];
  const int tx = threadIdx.x & 15, ty = threadIdx.x >> 4;
  const int sb = blockIdx.x, bh = blockIdx.y;
  const __hip_bfloat16* inp = in + (long)bh * 2048 * 64;
  __hip_bfloat16* outp = out + (long)bh * 64 * 2048;
  for (int i = 0; i < 4; ++i)
    for (int j = 0; j < 4; ++j)
      t[ty*4+i][tx*4+j] = inp[(long)(sb*64 + ty*4+i)*64 + tx*4 + j];
  __syncthreads();
  for (int i = 0; i < 4; ++i)
    for (int j = 0; j < 4; ++j)
      outp[(long)(ty*4+i)*2048 + sb*64 + tx*4 + j] = t[tx*4+j][ty*4+i];
}

// ---------------------------------------------------------------- 128x128 bf16 GEMM, B^T input
// m97 structure: global_load_lds width-16 staging for BOTH A and B (bf16).
// Swapped-operand MFMA -> lane = output row, regs = 4 consecutive output cols.
// EPI 0: fused QKV projections (blockIdx.z), bf16 out [b][h][s][d]
// EPI 2: f32 out + bias[col] + resid, float4 stores
template<int EPI>
__global__ __launch_bounds__(256)
void gemm_bt(const __hip_bfloat16* __restrict__ A0,
             const __hip_bfloat16* __restrict__ A1,
             const __hip_bfloat16* __restrict__ A2,
             const __hip_bfloat16* __restrict__ B0,
             const __hip_bfloat16* __restrict__ B1,
             const __hip_bfloat16* __restrict__ B2,
             void* __restrict__ out,
             const float* __restrict__ bias,
             const float* __restrict__ resid,
             int M, int N, int K)
{
  const int z = (EPI == 0) ? blockIdx.z : 0;
  const __hip_bfloat16* A  = z == 0 ? A0 : z == 1 ? A1 : A2;
  const __hip_bfloat16* Bt = z == 0 ? B0 : z == 1 ? B1 : B2;
  // fold log2(e) into the Q scale so attn uses exp2 directly
  const float scale = (EPI == 0 && z == 0) ? 0.045084219f : 1.0f;

  __shared__ __hip_bfloat16 As[128*32];
  __shared__ __hip_bfloat16 Bs[128*32];
  const int tid = threadIdx.x;
  const int wid = tid >> 6;
  const int lane = tid & 63;
  const int lr = lane & 15, lg = lane >> 4;
  const int bm = blockIdx.y, bn = blockIdx.x;
  const int wm = wid >> 1, wn = wid & 1;

  f32x4 acc[4][4] = {};

  const int srow = tid >> 2;          // 0..63
  const int scol = (tid & 3) * 8;
  const __hip_bfloat16* Ag = A  + (long)(bm*128 + srow)*K + scol;
  const __hip_bfloat16* Bg = Bt + (long)(bn*128 + srow)*K + scol;
  __hip_bfloat16* AsW = &As[wid*512];
  __hip_bfloat16* BsW = &Bs[wid*512];

  for (int k0 = 0; k0 < K; k0 += 32) {
    GLOAD16(Ag + k0,          AsW);
    GLOAD16(Ag + 64*K + k0,   AsW + 2048);
    GLOAD16(Bg + k0,          BsW);
    GLOAD16(Bg + 64*K + k0,   BsW + 2048);
    __syncthreads();
    bf16x8 a[4], b[4];
    for (int m = 0; m < 4; ++m)
      a[m] = *(const bf16x8*)&As[(wm*64 + m*16 + lr)*32 + lg*8];
    for (int n = 0; n < 4; ++n)
      b[n] = *(const bf16x8*)&Bs[(wn*64 + n*16 + lr)*32 + lg*8];
    for (int m = 0; m < 4; ++m)
      for (int n = 0; n < 4; ++n)
        acc[m][n] = __builtin_amdgcn_mfma_f32_16x16x32_bf16(b[n], a[m], acc[m][n], 0, 0, 0);
    __syncthreads();
  }

  for (int m = 0; m < 4; ++m) {
    const int grow = bm*128 + wm*64 + m*16 + lr;
    for (int n = 0; n < 4; ++n) {
      const int c0 = bn*128 + wn*64 + n*16 + lg*4;
      if (EPI == 0) {
        const int b_ = grow >> 11, s = grow & 2047;
        const int h = c0 >> 6, d = c0 & 63;
        uint2 pk;
        pk.x = pack_bf16_2(acc[m][n][0]*scale, acc[m][n][1]*scale);
        pk.y = pack_bf16_2(acc[m][n][2]*scale, acc[m][n][3]*scale);
        *(uint2*)((__hip_bfloat16*)out + (long)z*4194304 +
                  ((long)(b_*16 + h)*2048 + s)*64 + d) = pk;
      } else {
        float4 b4 = *(const float4*)(bias + c0);
        float4 r4 = *(const float4*)(resid + (long)grow*N + c0);
        float4 o4;
        o4.x = acc[m][n][0] + b4.x + r4.x;
        o4.y = acc[m][n][1] + b4.y + r4.y;
        o4.z = acc[m][n][2] + b4.z + r4.z;
        o4.w = acc[m][n][3] + b4.w + r4.w;
        *(float4*)((float*)out + (long)grow*N + c0) = o4;
      }
    }
  }
}

// ---------------------------------------------------------------- attention
// R11 attn + ONE change: pass 1 now uses the same register K double-buffer
// prefetch idiom as pass 2 (R9's negative A/B proved the prefetch is
// load-bearing; pass 1 previously ate full L2 latency on every kt).
__global__ __launch_bounds__(256)
void attn_kernel(const __hip_bfloat16* __restrict__ Qh,
                 const __hip_bfloat16* __restrict__ Kh,
                 const __hip_bfloat16* __restrict__ Vt,
                 float* __restrict__ attn_out,
                 __hip_bfloat16* __restrict__ O)
{
  __shared__ __hip_bfloat16 Ps[64*128];
  __shared__ float red[4][64];
  __shared__ float invl[64];

  const int tid = threadIdx.x, wid = tid >> 6, lane = tid & 63;
  const int lr = lane & 15, lg = lane >> 4;
  // XCD swizzle: physical block b (XCD = b%8) -> logical orig = (b%8)*128 + b/8
  const int orig = (blockIdx.x & 7) * 128 + (blockIdx.x >> 3);
  const int bh = orig >> 5, qb = orig & 31;

  const __hip_bfloat16* Qlane = Qh + ((long)bh*2048 + qb*64 + lr)*64 + lg*8;
  const __hip_bfloat16* Klane = Kh + (long)bh*2048*64 + (long)(wid*32 + lr)*64 + lg*8;
  const __hip_bfloat16* Vlane = Vt + (long)bh*64*2048 + (long)(wid*16 + lr)*2048 + lg*8;

  bf16x8 aq[4][2];
  for (int mq = 0; mq < 4; ++mq)
    for (int kk = 0; kk < 2; ++kk)
      aq[mq][kk] = *(const bf16x8*)(Qlane + mq*1024 + kk*32);

  // ---- pass 1: row sums of exp2(S') — barrier-free, register K prefetch
  float rs[4] = {0.f, 0.f, 0.f, 0.f};
  {
    bf16x8 bk[2][2];
#pragma unroll
    for (int nk = 0; nk < 2; ++nk)
      for (int kk = 0; kk < 2; ++kk)
        bk[nk][kk] = *(const bf16x8*)(Klane + nk*1024 + kk*32);

#pragma unroll 1
    for (int kt = 0; kt < 16; ++kt) {
      f32x4 s2[4][2] = {};
      __builtin_amdgcn_s_setprio(1);
#pragma unroll
      for (int mq = 0; mq < 4; ++mq)
        for (int nk = 0; nk < 2; ++nk)
          for (int kk = 0; kk < 2; ++kk)
            s2[mq][nk] = __builtin_amdgcn_mfma_f32_16x16x32_bf16(bk[nk][kk], aq[mq][kk], s2[mq][nk], 0, 0, 0);
      __builtin_amdgcn_s_setprio(0);

      // prefetch next tile's K fragments (land during the exp2/accumulate phase)
      bf16x8 nbk[2][2];
      if (kt < 15) {
#pragma unroll
        for (int nk = 0; nk < 2; ++nk)
          for (int kk = 0; kk < 2; ++kk)
            nbk[nk][kk] = *(const bf16x8*)(Klane + (kt+1)*8192 + nk*1024 + kk*32);
      }

#pragma unroll
      for (int mq = 0; mq < 4; ++mq)
        for (int nk = 0; nk < 2; ++nk)
          for (int jj = 0; jj < 4; ++jj)
            rs[mq] += exp2f(s2[mq][nk][jj]);

#pragma unroll
      for (int nk = 0; nk < 2; ++nk)
        for (int kk = 0; kk < 2; ++kk)
          bk[nk][kk] = nbk[nk][kk];
    }
  }

  for (int mq = 0; mq < 4; ++mq) {
    float e = rs[mq];
    e += __shfl_xor(e, 16);
    e += __shfl_xor(e, 32);
    rs[mq] = e;
  }
  if (lg == 0)
    for (int mq = 0; mq < 4; ++mq)
      red[wid][mq*16 + lr] = rs[mq];
  __syncthreads();
  if (tid < 64)
    invl[tid] = 1.0f / (red[0][tid] + red[1][tid] + red[2][tid] + red[3][tid]);
  __syncthreads();

  float iv[4];
  for (int mq = 0; mq < 4; ++mq) iv[mq] = invl[mq*16 + lr];

  // ---- pass 2 (register K/V double-buffer prefetch)
  f32x4 acc_o[4] = {};
  float* attn_row = attn_out + ((long)bh*2048 + qb*64)*2048;

  bf16x8 bk[2][2], vb[4];
#pragma unroll
  for (int nk = 0; nk < 2; ++nk)
    for (int kk = 0; kk < 2; ++kk)
      bk[nk][kk] = *(const bf16x8*)(Klane + nk*1024 + kk*32);
#pragma unroll
  for (int k2 = 0; k2 < 4; ++k2)
    vb[k2] = *(const bf16x8*)(Vlane + k2*32);

#pragma unroll 1
  for (int kt = 0; kt < 16; ++kt) {
    f32x4 s2[4][2] = {};
    __builtin_amdgcn_s_setprio(1);
#pragma unroll
    for (int mq = 0; mq < 4; ++mq)
      for (int nk = 0; nk < 2; ++nk)
        for (int kk = 0; kk < 2; ++kk)
          s2[mq][nk] = __builtin_amdgcn_mfma_f32_16x16x32_bf16(bk[nk][kk], aq[mq][kk], s2[mq][nk], 0, 0, 0);
    __builtin_amdgcn_s_setprio(0);

    // prefetch next tile's K/V fragments (land during exp/store phase)
    bf16x8 nbk[2][2], nvb[4];
    if (kt < 15) {
#pragma unroll
      for (int nk = 0; nk < 2; ++nk)
        for (int kk = 0; kk < 2; ++kk)
          nbk[nk][kk] = *(const bf16x8*)(Klane + (kt+1)*8192 + nk*1024 + kk*32);
#pragma unroll
      for (int k2 = 0; k2 < 4; ++k2)
        nvb[k2] = *(const bf16x8*)(Vlane + (kt+1)*128 + k2*32);
    }

#pragma unroll
    for (int mq = 0; mq < 4; ++mq) {
      const int row = mq*16 + lr;
      for (int nk = 0; nk < 2; ++nk) {
        const int kc = wid*32 + nk*16 + lg*4;
        f32x4 p;
        p[0] = exp2f(s2[mq][nk][0]) * iv[mq];
        p[1] = exp2f(s2[mq][nk][1]) * iv[mq];
        p[2] = exp2f(s2[mq][nk][2]) * iv[mq];
        p[3] = exp2f(s2[mq][nk][3]) * iv[mq];
        __builtin_nontemporal_store(p, (f32x4*)(attn_row + (long)row*2048 + kt*128 + kc));
        uint2 pb;
        pb.x = pack_bf16_2(p[0], p[1]);
        pb.y = pack_bf16_2(p[2], p[3]);
        const int boff = (row*256 + kc*2) ^ ((row & 15) << 4);
        *(uint2*)((char*)Ps + boff) = pb;
      }
    }
    __syncthreads();

    __builtin_amdgcn_s_setprio(1);
#pragma unroll
    for (int mq = 0; mq < 4; ++mq) {
      const int row = mq*16 + lr;
      for (int k2 = 0; k2 < 4; ++k2) {
        const int boff = (row*256 + (k2*32 + lg*8)*2) ^ ((row & 15) << 4);
        bf16x8 pa = *(const bf16x8*)((char*)Ps + boff);
        acc_o[mq] = __builtin_amdgcn_mfma_f32_16x16x32_bf16(vb[k2], pa, acc_o[mq], 0, 0, 0);
      }
    }
    __builtin_amdgcn_s_setprio(0);
    __syncthreads();

#pragma unroll
    for (int nk = 0; nk < 2; ++nk)
      for (int kk = 0; kk < 2; ++kk)
        bk[nk][kk] = nbk[nk][kk];
#pragma unroll
    for (int k2 = 0; k2 < 4; ++k2)
      vb[k2] = nvb[k2];
  }

  const int b_ = bh >> 4, h = bh & 15;
  for (int mq = 0; mq < 4; ++mq) {
    const long grow = (long)b_*2048 + qb*64 + mq*16 + lr;
    const int col = h*64 + wid*16 + lg*4;
    uint2 pk;
    pk.x = pack_bf16_2(acc_o[mq][0], acc_o[mq][1]);
    pk.y = pack_bf16_2(acc_o[mq][2], acc_o[mq][3]);
    *(uint2*)(O + grow*1024 + col) = pk;
  }
}

// ---------------------------------------------------------------- layernorm
__global__ __launch_bounds__(256)
void ln_kernel(const float* __restrict__ xin, const float* __restrict__ gam,
               const float* __restrict__ bet, float* __restrict__ xout)
{
  const int row = blockIdx.x;
  const int tid = threadIdx.x;
  const float* xr = xin + (long)row*1024;
  float4 v = *(const float4*)(xr + tid*4);
  float s  = v.x + v.y + v.z + v.w;
  float ss = v.x*v.x + v.y*v.y + v.z*v.z + v.w*v.w;
  for (int o = 1; o < 64; o <<= 1) {
    s  += __shfl_xor(s, o, 64);
    ss += __shfl_xor(ss, o, 64);
  }
  __shared__ float rsh[4], rssh[4];
  const int wid = tid >> 6, lane = tid & 63;
  if (lane == 0) { rsh[wid] = s; rssh[wid] = ss; }
  __syncthreads();
  s  = rsh[0] + rsh[1] + rsh[2] + rsh[3];
  ss = rssh[0] + rssh[1] + rssh[2] + rssh[3];
  const float mean = s * (1.0f/1024.0f);
  const float var  = ss * (1.0f/1024.0f) - mean*mean;
  const float rstd = rsqrtf(var + 1e-5f);
  float4 g4 = *(const float4*)(gam + tid*4);
  float4 b4 = *(const float4*)(bet + tid*4);
  float4 o4;
  o4.x = (v.x - mean)*rstd*g4.x + b4.x;
  o4.y = (v.y - mean)*rstd*g4.y + b4.y;
  o4.z = (v.z - mean)*rstd*g4.z + b4.z;
  o4.w = (v.w - mean)*rstd*g4.w + b4.w;
  *(float4*)(xout + (long)row*1024 + tid*4) = o4;
}

// ---------------------------------------------------------------- launch
extern "C" void kernel_launch(void* const* d_in, const int* in_sizes, int n_in,
                              void* d_out, int out_size, void* d_ws, size_t ws_size,
                              hipStream_t stream)
{
  (void)in_sizes; (void)n_in; (void)out_size; (void)ws_size;
  const float* q    = (const float*)d_in[0];
  const float* k    = (const float*)d_in[1];
  const float* v    = (const float*)d_in[2];
  const float* w_q  = (const float*)d_in[3];
  const float* w_k  = (const float*)d_in[4];
  const float* w_v  = (const float*)d_in[5];
  const float* w_fc = (const float*)d_in[6];
  const float* b_fc = (const float*)d_in[7];
  const float* ln_g = (const float*)d_in[8];
  const float* ln_b = (const float*)d_in[9];

  const long MB = 1024*1024;
  char* ws = (char*)d_ws;
  __hip_bfloat16* q_bf  = (__hip_bfloat16*)(ws);
  __hip_bfloat16* k_bf  = (__hip_bfloat16*)(ws +  8*MB);
  __hip_bfloat16* v_bf  = (__hip_bfloat16*)(ws + 16*MB);
  __hip_bfloat16* wq_t  = (__hip_bfloat16*)(ws + 24*MB);
  __hip_bfloat16* wk_t  = (__hip_bfloat16*)(ws + 26*MB);
  __hip_bfloat16* wv_t  = (__hip_bfloat16*)(ws + 28*MB);
  __hip_bfloat16* wfc_t = (__hip_bfloat16*)(ws + 30*MB);
  __hip_bfloat16* QKVh  = (__hip_bfloat16*)(ws + 32*MB);   // Qh|Kh|Vh, 8MB each
  __hip_bfloat16* Qh    = QKVh;
  __hip_bfloat16* Kh    = QKVh + 4194304L;
  __hip_bfloat16* Vh    = QKVh + 8388608L;
  __hip_bfloat16* Vht   = (__hip_bfloat16*)(ws + 56*MB);
  __hip_bfloat16* Obuf  = (__hip_bfloat16*)(ws + 64*MB);
  float*          xbuf  = (float*)(ws + 72*MB);

  float* x_out    = (float*)d_out;
  float* attn_out = x_out + 4194304L;

  prep_kernel<<<7168, 256, 0, stream>>>(q, k, v, q_bf, k_bf, v_bf,
                                        w_q, w_k, w_v, w_fc,
                                        wq_t, wk_t, wv_t, wfc_t);

  gemm_bt<0><<<dim3(8, 32, 3), 256, 0, stream>>>(q_bf, k_bf, v_bf,
                                                 wq_t, wk_t, wv_t,
                                                 QKVh, nullptr, nullptr, 4096, 1024, 1024);

  vtrans_kernel<<<dim3(32, 32), 256, 0, stream>>>(Vh, Vht);

  attn_kernel<<<1024, 256, 0, stream>>>(Qh, Kh, Vht, attn_out, Obuf);

  gemm_bt<2><<<dim3(8, 32), 256, 0, stream>>>(Obuf, nullptr, nullptr,
                                              wfc_t, nullptr, nullptr,
                                              xbuf, b_fc, q, 4096, 1024, 1024);

  ln_kernel<<<4096, 256, 0, stream>>>(xbuf, ln_g, ln_b, x_out);
}